// Round 5
// baseline (2818.315 us; speedup 1.0000x reference)
//
#include <hip/hip_runtime.h>
#include <cstdint>
#include <cstddef>

#define NB   256        // graphs
#define EPG  8192       // edge slots per graph
#define H    128
#define OUTD 10
#define ETOT (NB * EPG) // 2097152

// ---------------------------------------------------------------------------
// K1: aggregation  agg[dst] += x[src]  (per-graph LDS accumulation)
// grid = NB * q, block = 256, q = n/128. WG handles graph b, node chunk qi.
// ---------------------------------------------------------------------------
__global__ __launch_bounds__(256) void k_agg(const float* __restrict__ xg,
                                             const int* __restrict__ e0,
                                             const int* __restrict__ e1,
                                             const int2* __restrict__ epk,
                                             int packed,
                                             float* __restrict__ agg,
                                             int n, int q)
{
    __shared__ float sh[128 * H];   // 64 KiB
    const int b   = blockIdx.x / q;
    const int qi  = blockIdx.x % q;
    const int tid = threadIdx.x;

    float4* sh4 = (float4*)sh;
    for (int i = tid; i < 128 * H / 4; i += 256) sh4[i] = make_float4(0.f, 0.f, 0.f, 0.f);
    __syncthreads();

    const int lane  = tid & 63;
    const int w     = tid >> 6;          // wave id 0..3
    const int ebase = b * EPG;
    const int dbase = b * n + qi * 128;

    for (int e = ebase + w; e < ebase + EPG; e += 4) {
        int s, d;
        if (packed) { int2 p = epk[e]; s = p.x; d = p.y; }
        else        { s = e0[e]; d = e1[e]; }
        unsigned dl = (unsigned)(d - dbase);
        if (s >= 0 && dl < 128u) {
            const float* xr = xg + (size_t)s * H;
            float v0 = xr[lane];
            float v1 = xr[lane + 64];
            atomicAdd(&sh[dl * H + lane],      v0);
            atomicAdd(&sh[dl * H + lane + 64], v1);
        }
    }
    __syncthreads();

    float4* ag4 = (float4*)(agg + (size_t)dbase * H);
    for (int i = tid; i < 128 * H / 4; i += 256) ag4[i] = sh4[i];
}

// ---------------------------------------------------------------------------
// K2: h = relu(agg @ Wrel + brel + x @ Wroot)   [Ncur,128] x [128,128] (x2)
// grid = Ncur/128, block = 256. WG tile 128 rows x 128 cols, thread 8x8.
// ---------------------------------------------------------------------------
__device__ __forceinline__ void fma4(float4& acc, float a, const float4& w)
{
    acc.x += a * w.x; acc.y += a * w.y; acc.z += a * w.z; acc.w += a * w.w;
}

__global__ __launch_bounds__(256) void k_gemm(const float* __restrict__ agg,
                                              const float* __restrict__ xg,
                                              const float* __restrict__ Wrel,
                                              const float* __restrict__ brel,
                                              const float* __restrict__ Wroot,
                                              float* __restrict__ hout)
{
    __shared__ float sA[128 * 16];   // 8 KiB  (rows x k-slice of agg)
    __shared__ float sX[128 * 16];   // 8 KiB
    __shared__ float sWr[16 * H];    // 16 KiB
    __shared__ float sWo[16 * H];    // 16 KiB

    const int tid = threadIdx.x;
    const size_t rowbase = (size_t)blockIdx.x * 128;
    const int rt = tid >> 4;   // 0..15 -> rows rt + 16*i
    const int ct = tid & 15;   // 0..15 -> cols ct*4..ct*4+3  and  64+ct*4..

    float4 accA[8], accB[8];
#pragma unroll
    for (int i = 0; i < 8; i++) {
        accA[i] = make_float4(0.f, 0.f, 0.f, 0.f);
        accB[i] = make_float4(0.f, 0.f, 0.f, 0.f);
    }

    const float4* gA = (const float4*)agg;
    const float4* gX = (const float4*)xg;
    const float4* gWr = (const float4*)Wrel;
    const float4* gWo = (const float4*)Wroot;

    for (int kb = 0; kb < 8; kb++) {
        __syncthreads();
        // stage rows: 128 x 16 floats = 512 float4 each
#pragma unroll
        for (int j = 0; j < 2; j++) {
            int f = tid + j * 256;            // 0..511
            int r = f >> 2, c4 = f & 3;
            ((float4*)sA)[f] = gA[(rowbase + r) * 32 + kb * 4 + c4];
            ((float4*)sX)[f] = gX[(rowbase + r) * 32 + kb * 4 + c4];
        }
        // stage W: 16 x 128 floats = 512 float4 each
#pragma unroll
        for (int j = 0; j < 2; j++) {
            int f = tid + j * 256;
            int r = f >> 5, c4 = f & 31;
            ((float4*)sWr)[f] = gWr[(kb * 16 + r) * 32 + c4];
            ((float4*)sWo)[f] = gWo[(kb * 16 + r) * 32 + c4];
        }
        __syncthreads();

#pragma unroll
        for (int k4 = 0; k4 < 4; k4++) {
            float4 a[8], xv[8];
#pragma unroll
            for (int i = 0; i < 8; i++) {
                int r = rt + 16 * i;
                a[i]  = ((float4*)sA)[r * 4 + k4];
                xv[i] = ((float4*)sX)[r * 4 + k4];
            }
#pragma unroll
            for (int kk = 0; kk < 4; kk++) {
                int krow = k4 * 4 + kk;
                float4 wr0 = ((float4*)sWr)[krow * 32 + ct];
                float4 wr1 = ((float4*)sWr)[krow * 32 + 16 + ct];
                float4 wo0 = ((float4*)sWo)[krow * 32 + ct];
                float4 wo1 = ((float4*)sWo)[krow * 32 + 16 + ct];
#pragma unroll
                for (int i = 0; i < 8; i++) {
                    float av  = (kk == 0) ? a[i].x  : (kk == 1) ? a[i].y  : (kk == 2) ? a[i].z  : a[i].w;
                    float xvv = (kk == 0) ? xv[i].x : (kk == 1) ? xv[i].y : (kk == 2) ? xv[i].z : xv[i].w;
                    fma4(accA[i], av,  wr0);
                    fma4(accA[i], xvv, wo0);
                    fma4(accB[i], av,  wr1);
                    fma4(accB[i], xvv, wo1);
                }
            }
        }
    }

    const float4 br0 = ((const float4*)brel)[ct];
    const float4 br1 = ((const float4*)brel)[16 + ct];
    float4* gH = (float4*)hout;
#pragma unroll
    for (int i = 0; i < 8; i++) {
        int r = rt + 16 * i;
        float4 o0, o1;
        o0.x = fmaxf(accA[i].x + br0.x, 0.f);
        o0.y = fmaxf(accA[i].y + br0.y, 0.f);
        o0.z = fmaxf(accA[i].z + br0.z, 0.f);
        o0.w = fmaxf(accA[i].w + br0.w, 0.f);
        o1.x = fmaxf(accB[i].x + br1.x, 0.f);
        o1.y = fmaxf(accB[i].y + br1.y, 0.f);
        o1.z = fmaxf(accB[i].z + br1.z, 0.f);
        o1.w = fmaxf(accB[i].w + br1.w, 0.f);
        gH[(rowbase + r) * 32 + ct]      = o0;
        gH[(rowbase + r) * 32 + 16 + ct] = o1;
    }
}

// ---------------------------------------------------------------------------
// XLA/Eigen f32 fast-tanh: clamp to +-7.90531110763549805, degree-13/6
// rational; |x| < 0.0004 -> identity. This is bit-level what jax computes.
// ---------------------------------------------------------------------------
__device__ __forceinline__ float xla_tanhf(float xin)
{
    const float plus_clamp  =  7.90531110763549805f;
    const float alpha_1  = 4.89352455891786e-03f;
    const float alpha_3  = 6.37261928875436e-04f;
    const float alpha_5  = 1.48572235717979e-05f;
    const float alpha_7  = 5.12229709037114e-08f;
    const float alpha_9  = -8.60467152213735e-11f;
    const float alpha_11 = 2.00018790482477e-13f;
    const float alpha_13 = -2.76076847742355e-16f;
    const float beta_0   = 4.89352518554385e-03f;
    const float beta_2   = 2.26843463243900e-03f;
    const float beta_4   = 1.18534705686654e-04f;
    const float beta_6   = 1.19825839466702e-06f;

    float x = fminf(fmaxf(xin, -plus_clamp), plus_clamp);
    float x2 = x * x;
    float p = fmaf(x2, alpha_13, alpha_11);
    p = fmaf(x2, p, alpha_9);
    p = fmaf(x2, p, alpha_7);
    p = fmaf(x2, p, alpha_5);
    p = fmaf(x2, p, alpha_3);
    p = fmaf(x2, p, alpha_1);
    p = x * p;
    float q = fmaf(x2, beta_6, beta_4);
    q = fmaf(x2, q, beta_2);
    q = fmaf(x2, q, beta_0);
    float r = p / q;
    return (fabsf(xin) < 0.0004f) ? xin : r;
}

// ---------------------------------------------------------------------------
// K3: z = (h·w)/||w|| (f64 reduce for determinism, cast f32), score =
//     xla_tanhf(z) — bit-level jax semantics incl. the z>7.9053 tie block.
//     skey = order-preserving u32 map of the f32 score bits.
// grid = Ncur/2, block = 256 (two rows per WG).
// ---------------------------------------------------------------------------
__global__ __launch_bounds__(256) void k_score(const float* __restrict__ h,
                                               const float* __restrict__ w,
                                               float* __restrict__ score,
                                               unsigned int* __restrict__ skey)
{
    __shared__ double red[8];
    const int tid = threadIdx.x;
    const int sub = tid >> 7;        // 0/1: which row of the pair
    const int c   = tid & 127;
    const int r   = blockIdx.x * 2 + sub;

    double wv = (double)w[c];
    double p  = (double)h[(size_t)r * H + c] * wv;
    double pw = wv * wv;
#pragma unroll
    for (int off = 32; off; off >>= 1) {
        p  += __shfl_down(p, off);
        pw += __shfl_down(pw, off);
    }
    const int wid = tid >> 6;        // 0..3
    if ((tid & 63) == 0) { red[wid] = p; red[4 + wid] = pw; }
    __syncthreads();
    if ((tid & 127) == 0) {
        double dot = red[sub * 2] + red[sub * 2 + 1];
        double nr2 = red[4 + sub * 2] + red[5 + sub * 2];
        float z  = (float)(dot / sqrt(nr2));
        float sc = xla_tanhf(z);
        score[r] = sc;
        unsigned u = __float_as_uint(sc);
        u = (u & 0x80000000u) ? ~u : (u | 0x80000000u);  // monotone map
        skey[r] = u;
    }
}

// ---------------------------------------------------------------------------
// K4: per-graph top-k: single-u64 bitonic sort, key = (f32-score-map << 32)
//     | (n-1-j)  ->  descending sort == (score desc, index asc), exactly
//     jax/np stable tie-break.  Then gather, readout, edge relabel.
// grid = NB, block = 256.
// ---------------------------------------------------------------------------
__global__ __launch_bounds__(256) void k_pool(const float* __restrict__ h,
                                              const float* __restrict__ score,
                                              const unsigned int* __restrict__ skey,
                                              const int* __restrict__ e0,
                                              const int* __restrict__ e1,
                                              int2* __restrict__ epk,
                                              int packed_in, int do_edges,
                                              float* __restrict__ xnew,
                                              float* __restrict__ g,
                                              int n, int k, int level0)
{
    __shared__ unsigned long long keys[512];
    __shared__ int   newid[512];
    __shared__ float red[512];

    const int b   = blockIdx.x;
    const int tid = threadIdx.x;

    for (int j = tid; j < n; j += 256)
        keys[j] = ((unsigned long long)skey[b * n + j] << 32) | (unsigned)(n - 1 - j);
    __syncthreads();

    // --- bitonic sort, DESCENDING (ties -> lower original index first)
    for (int kk = 2; kk <= n; kk <<= 1) {
        for (int jj = kk >> 1; jj > 0; jj >>= 1) {
            for (int i = tid; i < n; i += 256) {
                int ixj = i ^ jj;
                if (ixj > i) {
                    unsigned long long a = keys[i], c = keys[ixj];
                    bool up = ((i & kk) == 0);
                    bool sw = up ? (a < c) : (a > c);
                    if (sw) { keys[i] = c; keys[ixj] = a; }
                }
            }
            __syncthreads();
        }
    }

    // --- new_id map
    for (int j = tid; j < n; j += 256) newid[j] = -1;
    __syncthreads();
    for (int p = tid; p < k; p += 256) {
        int j = n - 1 - (int)(keys[p] & 0xFFFFFFFFu);
        newid[j] = p;
    }
    __syncthreads();

    // --- gather gated nodes + mean/max readout
    const int c   = tid & 127;
    const int grp = tid >> 7;     // 0/1
    float sm = 0.f, mx = -3.4e38f;
    for (int p = grp; p < k; p += 2) {
        int j    = n - 1 - (int)(keys[p] & 0xFFFFFFFFu);
        int oldg = b * n + j;
        float sc = score[oldg];
        float v  = h[(size_t)oldg * H + c] * sc;
        xnew[((size_t)(b * k + p)) * H + c] = v;
        sm += v;
        mx = fmaxf(mx, v);
    }
    red[tid]       = sm;
    red[256 + tid] = mx;
    __syncthreads();
    if (tid < 128) {
        float mean = (red[tid] + red[tid + 128]) / (float)k;
        float mmax = fmaxf(red[256 + tid], red[256 + tid + 128]);
        size_t gi = (size_t)b * 256 + tid;
        if (level0) { g[gi] = mean;  g[gi + 128] = mmax; }
        else        { g[gi] += mean; g[gi + 128] += mmax; }
    }

    // --- edge relabel + masking (sentinel -1)
    if (do_edges) {
        for (int e = b * EPG + tid; e < (b + 1) * EPG; e += 256) {
            int s, d;
            if (packed_in) { int2 pr = epk[e]; s = pr.x; d = pr.y; }
            else           { s = e0[e]; d = e1[e]; }
            int2 outp = make_int2(-1, -1);
            if (s >= 0) {
                int ns = newid[s - b * n];
                int nd = newid[d - b * n];
                if (ns >= 0 && nd >= 0) outp = make_int2(b * k + ns, b * k + nd);
            }
            epk[e] = outp;
        }
    }
}

// ---------------------------------------------------------------------------
// K5: out = relu(g @ W1 + b1) @ W2 + b2.  grid = NB, block = 128.
// ---------------------------------------------------------------------------
__global__ __launch_bounds__(128) void k_head(const float* __restrict__ g,
                                              const float* __restrict__ W1,
                                              const float* __restrict__ b1,
                                              const float* __restrict__ W2,
                                              const float* __restrict__ b2,
                                              float* __restrict__ out)
{
    __shared__ float hid[H];
    const int b = blockIdx.x, tid = threadIdx.x;
    float acc = b1[tid];
    const float* gr = g + (size_t)b * 256;
    for (int j = 0; j < 256; j++) acc += gr[j] * W1[j * H + tid];
    hid[tid] = fmaxf(acc, 0.f);
    __syncthreads();
    if (tid < OUTD) {
        float o = b2[tid];
        for (int hh = 0; hh < H; hh++) o += hid[hh] * W2[hh * OUTD + tid];
        out[b * OUTD + tid] = o;
    }
}

// ---------------------------------------------------------------------------
extern "C" void kernel_launch(void* const* d_in, const int* in_sizes, int n_in,
                              void* d_out, int out_size, void* d_ws, size_t ws_size,
                              hipStream_t stream)
{
    const float* x     = (const float*)d_in[0];
    const int*   ei    = (const int*)  d_in[1];
    const float* Wrel  = (const float*)d_in[2];
    const float* brel  = (const float*)d_in[3];
    const float* Wroot = (const float*)d_in[4];
    const float* poolw = (const float*)d_in[5];
    const float* W1    = (const float*)d_in[6];
    const float* b1    = (const float*)d_in[7];
    const float* W2    = (const float*)d_in[8];
    const float* b2    = (const float*)d_in[9];
    float* out = (float*)d_out;

    char* ws = (char*)d_ws;
    float* agg   = (float*)(ws);                            // 64 MiB
    float* hbuf  = (float*)(ws + 67108864);                 // 64 MiB
    float* xbuf  = (float*)(ws + 134217728);                // 32 MiB
    float* score = (float*)(ws + 167772160);                // 512 KiB
    unsigned int* skey = (unsigned int*)(ws + 168296448);   // 512 KiB
    int2*  epk   = (int2*) (ws + 168820736);                // 16 MiB
    float* g     = (float*)(ws + 185597952);                // 256 KiB

    const int ns[3] = {512, 256, 128};
    const float* xin = x;
    for (int lvl = 0; lvl < 3; lvl++) {
        const int n = ns[lvl], q = n / 128, k = n / 2;
        const int Ncur = NB * n;
        k_agg<<<NB * q, 256, 0, stream>>>(xin, ei, ei + ETOT, epk, lvl ? 1 : 0, agg, n, q);
        k_gemm<<<Ncur / 128, 256, 0, stream>>>(agg, xin, Wrel + lvl * H * H,
                                               brel + lvl * H, Wroot + lvl * H * H, hbuf);
        k_score<<<Ncur / 2, 256, 0, stream>>>(hbuf, poolw + lvl * H, score, skey);
        k_pool<<<NB, 256, 0, stream>>>(hbuf, score, skey, ei, ei + ETOT, epk,
                                       lvl ? 1 : 0, (lvl < 2) ? 1 : 0,
                                       xbuf, g, n, k, (lvl == 0) ? 1 : 0);
        xin = xbuf;
    }
    k_head<<<NB, 128, 0, stream>>>(g, W1, b1, W2, b2, out);
}

// Round 7
// 905.659 us; speedup vs baseline: 3.1119x; 3.1119x over previous
//
#include <hip/hip_runtime.h>
#include <cstdint>
#include <cstddef>

#define NB   256        // graphs
#define EPG  8192       // edge slots per graph
#define H    128
#define OUTD 10
#define ETOT (NB * EPG) // 2097152

// ---------------------------------------------------------------------------
// K1a: per-graph CSR build (counting sort by dst). grid = NB, block = 256.
// Two passes over the graph's 8192 edge slots; all atomics in LDS.
// ---------------------------------------------------------------------------
__global__ __launch_bounds__(256) void k_csr(const int* __restrict__ e0,
                                             const int* __restrict__ e1,
                                             const int2* __restrict__ epk,
                                             int packed,
                                             int* __restrict__ csr_src,
                                             int* __restrict__ rowptr,
                                             int* __restrict__ cnt,
                                             int n)
{
    __shared__ int hcnt[512];
    __shared__ int sa[512];
    __shared__ int sb[512];
    const int b = blockIdx.x, tid = threadIdx.x;
    const int nb = b * n;

    for (int j = tid; j < n; j += 256) hcnt[j] = 0;
    __syncthreads();

    // pass 1: histogram of dst
    for (int e = b * EPG + tid; e < (b + 1) * EPG; e += 256) {
        int s, d;
        if (packed) { int2 p = epk[e]; s = p.x; d = p.y; }
        else        { s = e0[e]; d = e1[e]; }
        if (s >= 0) atomicAdd(&hcnt[d - nb], 1);
    }
    __syncthreads();

    // Hillis-Steele inclusive scan (ping-pong sa/sb)
    for (int j = tid; j < n; j += 256) sa[j] = hcnt[j];
    __syncthreads();
    int* pa = sa; int* pb = sb;
    for (int st = 1; st < n; st <<= 1) {
        for (int j = tid; j < n; j += 256) {
            int v = pa[j];
            if (j >= st) v += pa[j - st];
            pb[j] = v;
        }
        __syncthreads();
        int* t = pa; pa = pb; pb = t;
    }
    // pa = inclusive scan; write rowptr/cnt, init cursor (pb) = exclusive
    for (int j = tid; j < n; j += 256) {
        int ex = j ? pa[j - 1] : 0;
        rowptr[nb + j] = b * EPG + ex;
        cnt[nb + j]    = hcnt[j];
        pb[j] = ex;
    }
    __syncthreads();

    // pass 2: scatter src ids
    for (int e = b * EPG + tid; e < (b + 1) * EPG; e += 256) {
        int s, d;
        if (packed) { int2 p = epk[e]; s = p.x; d = p.y; }
        else        { s = e0[e]; d = e1[e]; }
        if (s >= 0) {
            int pos = atomicAdd(&pb[d - nb], 1);
            csr_src[b * EPG + pos] = s;
        }
    }
}

// ---------------------------------------------------------------------------
// K1b: dense aggregation  agg[dst][c] = sum_j x[csr_src[j]][c].
// grid = Ncur/2, block = 256 (two dst rows per WG, 128 threads each).
// csr index loads are wave-broadcast; x-row loads are 512B coalesced.
// ---------------------------------------------------------------------------
__global__ __launch_bounds__(256) void k_gather(const float* __restrict__ xg,
                                                const int* __restrict__ csr_src,
                                                const int* __restrict__ rowptr,
                                                const int* __restrict__ cnt,
                                                float* __restrict__ agg)
{
    const int tid = threadIdx.x;
    const int dst = blockIdx.x * 2 + (tid >> 7);
    const int c   = tid & 127;
    const int p0  = rowptr[dst];
    const int pc  = cnt[dst];
    const int* sp = csr_src + p0;
    float acc = 0.f;
    int j = 0;
    for (; j + 4 <= pc; j += 4) {
        int s0 = sp[j], s1 = sp[j + 1], s2 = sp[j + 2], s3 = sp[j + 3];
        float v0 = xg[(size_t)s0 * H + c];
        float v1 = xg[(size_t)s1 * H + c];
        float v2 = xg[(size_t)s2 * H + c];
        float v3 = xg[(size_t)s3 * H + c];
        acc += v0; acc += v1; acc += v2; acc += v3;
    }
    for (; j < pc; j++) acc += xg[(size_t)csr_src[p0 + j] * H + c];
    agg[(size_t)dst * H + c] = acc;
}

// ---------------------------------------------------------------------------
// K2: h = relu(agg @ Wrel + brel + x @ Wroot)   [Ncur,128] x [128,128] (x2)
// grid = Ncur/128, block = 256. WG tile 128 rows x 128 cols, thread 8x8.
// ---------------------------------------------------------------------------
__device__ __forceinline__ void fma4(float4& acc, float a, const float4& w)
{
    acc.x += a * w.x; acc.y += a * w.y; acc.z += a * w.z; acc.w += a * w.w;
}

__global__ __launch_bounds__(256) void k_gemm(const float* __restrict__ agg,
                                              const float* __restrict__ xg,
                                              const float* __restrict__ Wrel,
                                              const float* __restrict__ brel,
                                              const float* __restrict__ Wroot,
                                              float* __restrict__ hout)
{
    __shared__ float sA[128 * 16];   // 8 KiB  (rows x k-slice of agg)
    __shared__ float sX[128 * 16];   // 8 KiB
    __shared__ float sWr[16 * H];    // 16 KiB
    __shared__ float sWo[16 * H];    // 16 KiB

    const int tid = threadIdx.x;
    const size_t rowbase = (size_t)blockIdx.x * 128;
    const int rt = tid >> 4;   // 0..15 -> rows rt + 16*i
    const int ct = tid & 15;   // 0..15 -> cols ct*4..ct*4+3  and  64+ct*4..

    float4 accA[8], accB[8];
#pragma unroll
    for (int i = 0; i < 8; i++) {
        accA[i] = make_float4(0.f, 0.f, 0.f, 0.f);
        accB[i] = make_float4(0.f, 0.f, 0.f, 0.f);
    }

    const float4* gA = (const float4*)agg;
    const float4* gX = (const float4*)xg;
    const float4* gWr = (const float4*)Wrel;
    const float4* gWo = (const float4*)Wroot;

    for (int kb = 0; kb < 8; kb++) {
        __syncthreads();
        // stage rows: 128 x 16 floats = 512 float4 each
#pragma unroll
        for (int j = 0; j < 2; j++) {
            int f = tid + j * 256;            // 0..511
            int r = f >> 2, c4 = f & 3;
            ((float4*)sA)[f] = gA[(rowbase + r) * 32 + kb * 4 + c4];
            ((float4*)sX)[f] = gX[(rowbase + r) * 32 + kb * 4 + c4];
        }
        // stage W: 16 x 128 floats = 512 float4 each
#pragma unroll
        for (int j = 0; j < 2; j++) {
            int f = tid + j * 256;
            int r = f >> 5, c4 = f & 31;
            ((float4*)sWr)[f] = gWr[(kb * 16 + r) * 32 + c4];
            ((float4*)sWo)[f] = gWo[(kb * 16 + r) * 32 + c4];
        }
        __syncthreads();

#pragma unroll
        for (int k4 = 0; k4 < 4; k4++) {
            float4 a[8], xv[8];
#pragma unroll
            for (int i = 0; i < 8; i++) {
                int r = rt + 16 * i;
                a[i]  = ((float4*)sA)[r * 4 + k4];
                xv[i] = ((float4*)sX)[r * 4 + k4];
            }
#pragma unroll
            for (int kk = 0; kk < 4; kk++) {
                int krow = k4 * 4 + kk;
                float4 wr0 = ((float4*)sWr)[krow * 32 + ct];
                float4 wr1 = ((float4*)sWr)[krow * 32 + 16 + ct];
                float4 wo0 = ((float4*)sWo)[krow * 32 + ct];
                float4 wo1 = ((float4*)sWo)[krow * 32 + 16 + ct];
#pragma unroll
                for (int i = 0; i < 8; i++) {
                    float av  = (kk == 0) ? a[i].x  : (kk == 1) ? a[i].y  : (kk == 2) ? a[i].z  : a[i].w;
                    float xvv = (kk == 0) ? xv[i].x : (kk == 1) ? xv[i].y : (kk == 2) ? xv[i].z : xv[i].w;
                    fma4(accA[i], av,  wr0);
                    fma4(accA[i], xvv, wo0);
                    fma4(accB[i], av,  wr1);
                    fma4(accB[i], xvv, wo1);
                }
            }
        }
    }

    const float4 br0 = ((const float4*)brel)[ct];
    const float4 br1 = ((const float4*)brel)[16 + ct];
    float4* gH = (float4*)hout;
#pragma unroll
    for (int i = 0; i < 8; i++) {
        int r = rt + 16 * i;
        float4 o0, o1;
        o0.x = fmaxf(accA[i].x + br0.x, 0.f);
        o0.y = fmaxf(accA[i].y + br0.y, 0.f);
        o0.z = fmaxf(accA[i].z + br0.z, 0.f);
        o0.w = fmaxf(accA[i].w + br0.w, 0.f);
        o1.x = fmaxf(accB[i].x + br1.x, 0.f);
        o1.y = fmaxf(accB[i].y + br1.y, 0.f);
        o1.z = fmaxf(accB[i].z + br1.z, 0.f);
        o1.w = fmaxf(accB[i].w + br1.w, 0.f);
        gH[(rowbase + r) * 32 + ct]      = o0;
        gH[(rowbase + r) * 32 + 16 + ct] = o1;
    }
}

// ---------------------------------------------------------------------------
// XLA/Eigen f32 fast-tanh: clamp to +-7.90531110763549805, degree-13/6
// rational; |x| < 0.0004 -> identity. This is bit-level what jax computes.
// ---------------------------------------------------------------------------
__device__ __forceinline__ float xla_tanhf(float xin)
{
    const float plus_clamp  =  7.90531110763549805f;
    const float alpha_1  = 4.89352455891786e-03f;
    const float alpha_3  = 6.37261928875436e-04f;
    const float alpha_5  = 1.48572235717979e-05f;
    const float alpha_7  = 5.12229709037114e-08f;
    const float alpha_9  = -8.60467152213735e-11f;
    const float alpha_11 = 2.00018790482477e-13f;
    const float alpha_13 = -2.76076847742355e-16f;
    const float beta_0   = 4.89352518554385e-03f;
    const float beta_2   = 2.26843463243900e-03f;
    const float beta_4   = 1.18534705686654e-04f;
    const float beta_6   = 1.19825839466702e-06f;

    float x = fminf(fmaxf(xin, -plus_clamp), plus_clamp);
    float x2 = x * x;
    float p = fmaf(x2, alpha_13, alpha_11);
    p = fmaf(x2, p, alpha_9);
    p = fmaf(x2, p, alpha_7);
    p = fmaf(x2, p, alpha_5);
    p = fmaf(x2, p, alpha_3);
    p = fmaf(x2, p, alpha_1);
    p = x * p;
    float q = fmaf(x2, beta_6, beta_4);
    q = fmaf(x2, q, beta_2);
    q = fmaf(x2, q, beta_0);
    float r = p / q;
    return (fabsf(xin) < 0.0004f) ? xin : r;
}

// ---------------------------------------------------------------------------
// K3: z = (h·w)/||w|| (f64 reduce for determinism, cast f32), score =
//     xla_tanhf(z) — bit-level jax semantics incl. the z>7.9053 tie block.
//     skey = order-preserving u32 map of the f32 score bits.
// grid = Ncur/2, block = 256 (two rows per WG).
// ---------------------------------------------------------------------------
__global__ __launch_bounds__(256) void k_score(const float* __restrict__ h,
                                               const float* __restrict__ w,
                                               float* __restrict__ score,
                                               unsigned int* __restrict__ skey)
{
    __shared__ double red[8];
    const int tid = threadIdx.x;
    const int sub = tid >> 7;        // 0/1: which row of the pair
    const int c   = tid & 127;
    const int r   = blockIdx.x * 2 + sub;

    double wv = (double)w[c];
    double p  = (double)h[(size_t)r * H + c] * wv;
    double pw = wv * wv;
#pragma unroll
    for (int off = 32; off; off >>= 1) {
        p  += __shfl_down(p, off);
        pw += __shfl_down(pw, off);
    }
    const int wid = tid >> 6;        // 0..3
    if ((tid & 63) == 0) { red[wid] = p; red[4 + wid] = pw; }
    __syncthreads();
    if ((tid & 127) == 0) {
        double dot = red[sub * 2] + red[sub * 2 + 1];
        double nr2 = red[4 + sub * 2] + red[5 + sub * 2];
        float z  = (float)(dot / sqrt(nr2));
        float sc = xla_tanhf(z);
        score[r] = sc;
        unsigned u = __float_as_uint(sc);
        u = (u & 0x80000000u) ? ~u : (u | 0x80000000u);  // monotone map
        skey[r] = u;
    }
}

// ---------------------------------------------------------------------------
// K4: per-graph top-k: single-u64 bitonic sort, key = (f32-score-map << 32)
//     | (n-1-j)  ->  descending sort == (score desc, index asc), exactly
//     jax/np stable tie-break.  Then gather, readout, edge relabel.
// grid = NB, block = 256.
// ---------------------------------------------------------------------------
__global__ __launch_bounds__(256) void k_pool(const float* __restrict__ h,
                                              const float* __restrict__ score,
                                              const unsigned int* __restrict__ skey,
                                              const int* __restrict__ e0,
                                              const int* __restrict__ e1,
                                              int2* __restrict__ epk,
                                              int packed_in, int do_edges,
                                              float* __restrict__ xnew,
                                              float* __restrict__ g,
                                              int n, int k, int level0)
{
    __shared__ unsigned long long keys[512];
    __shared__ int   newid[512];
    __shared__ float red[512];

    const int b   = blockIdx.x;
    const int tid = threadIdx.x;

    for (int j = tid; j < n; j += 256)
        keys[j] = ((unsigned long long)skey[b * n + j] << 32) | (unsigned)(n - 1 - j);
    __syncthreads();

    // --- bitonic sort, DESCENDING (ties -> lower original index first)
    for (int kk = 2; kk <= n; kk <<= 1) {
        for (int jj = kk >> 1; jj > 0; jj >>= 1) {
            for (int i = tid; i < n; i += 256) {
                int ixj = i ^ jj;
                if (ixj > i) {
                    unsigned long long a = keys[i], c = keys[ixj];
                    bool up = ((i & kk) == 0);
                    bool sw = up ? (a < c) : (a > c);
                    if (sw) { keys[i] = c; keys[ixj] = a; }
                }
            }
            __syncthreads();
        }
    }

    // --- new_id map
    for (int j = tid; j < n; j += 256) newid[j] = -1;
    __syncthreads();
    for (int p = tid; p < k; p += 256) {
        int j = n - 1 - (int)(keys[p] & 0xFFFFFFFFu);
        newid[j] = p;
    }
    __syncthreads();

    // --- gather gated nodes + mean/max readout
    const int c   = tid & 127;
    const int grp = tid >> 7;     // 0/1
    float sm = 0.f, mx = -3.4e38f;
    for (int p = grp; p < k; p += 2) {
        int j    = n - 1 - (int)(keys[p] & 0xFFFFFFFFu);
        int oldg = b * n + j;
        float sc = score[oldg];
        float v  = h[(size_t)oldg * H + c] * sc;
        xnew[((size_t)(b * k + p)) * H + c] = v;
        sm += v;
        mx = fmaxf(mx, v);
    }
    red[tid]       = sm;
    red[256 + tid] = mx;
    __syncthreads();
    if (tid < 128) {
        float mean = (red[tid] + red[tid + 128]) / (float)k;
        float mmax = fmaxf(red[256 + tid], red[256 + tid + 128]);
        size_t gi = (size_t)b * 256 + tid;
        if (level0) { g[gi] = mean;  g[gi + 128] = mmax; }
        else        { g[gi] += mean; g[gi + 128] += mmax; }
    }

    // --- edge relabel + masking (sentinel -1)
    if (do_edges) {
        for (int e = b * EPG + tid; e < (b + 1) * EPG; e += 256) {
            int s, d;
            if (packed_in) { int2 pr = epk[e]; s = pr.x; d = pr.y; }
            else           { s = e0[e]; d = e1[e]; }
            int2 outp = make_int2(-1, -1);
            if (s >= 0) {
                int ns = newid[s - b * n];
                int nd = newid[d - b * n];
                if (ns >= 0 && nd >= 0) outp = make_int2(b * k + ns, b * k + nd);
            }
            epk[e] = outp;
        }
    }
}

// ---------------------------------------------------------------------------
// K5: out = relu(g @ W1 + b1) @ W2 + b2.  grid = NB, block = 128.
// ---------------------------------------------------------------------------
__global__ __launch_bounds__(128) void k_head(const float* __restrict__ g,
                                              const float* __restrict__ W1,
                                              const float* __restrict__ b1,
                                              const float* __restrict__ W2,
                                              const float* __restrict__ b2,
                                              float* __restrict__ out)
{
    __shared__ float hid[H];
    const int b = blockIdx.x, tid = threadIdx.x;
    float acc = b1[tid];
    const float* gr = g + (size_t)b * 256;
    for (int j = 0; j < 256; j++) acc += gr[j] * W1[j * H + tid];
    hid[tid] = fmaxf(acc, 0.f);
    __syncthreads();
    if (tid < OUTD) {
        float o = b2[tid];
        for (int hh = 0; hh < H; hh++) o += hid[hh] * W2[hh * OUTD + tid];
        out[b * OUTD + tid] = o;
    }
}

// ---------------------------------------------------------------------------
extern "C" void kernel_launch(void* const* d_in, const int* in_sizes, int n_in,
                              void* d_out, int out_size, void* d_ws, size_t ws_size,
                              hipStream_t stream)
{
    const float* x     = (const float*)d_in[0];
    const int*   ei    = (const int*)  d_in[1];
    const float* Wrel  = (const float*)d_in[2];
    const float* brel  = (const float*)d_in[3];
    const float* Wroot = (const float*)d_in[4];
    const float* poolw = (const float*)d_in[5];
    const float* W1    = (const float*)d_in[6];
    const float* b1    = (const float*)d_in[7];
    const float* W2    = (const float*)d_in[8];
    const float* b2    = (const float*)d_in[9];
    float* out = (float*)d_out;

    char* ws = (char*)d_ws;
    float* agg     = (float*)(ws);                          // 64 MiB
    float* hbuf    = (float*)(ws + 67108864);               // 64 MiB
    float* xbuf    = (float*)(ws + 134217728);              // 32 MiB
    int2*  epk     = (int2*) (ws + 167772160);              // 16 MiB
    int*   csr     = (int*)  (ws + 184549376);              // 8 MiB
    int*   rowptr  = (int*)  (ws + 192937984);              // 512 KiB
    int*   cnt     = (int*)  (ws + 193462272);              // 512 KiB
    float* score   = (float*)(ws + 193986560);              // 512 KiB
    unsigned int* skey = (unsigned int*)(ws + 194510848);   // 512 KiB
    float* g       = (float*)(ws + 195035136);              // 256 KiB

    const int ns[3] = {512, 256, 128};
    const float* xin = x;
    for (int lvl = 0; lvl < 3; lvl++) {
        const int n = ns[lvl], k = n / 2;
        const int Ncur = NB * n;
        k_csr<<<NB, 256, 0, stream>>>(ei, ei + ETOT, epk, lvl ? 1 : 0,
                                      csr, rowptr, cnt, n);
        k_gather<<<Ncur / 2, 256, 0, stream>>>(xin, csr, rowptr, cnt, agg);
        k_gemm<<<Ncur / 128, 256, 0, stream>>>(agg, xin, Wrel + lvl * H * H,
                                               brel + lvl * H, Wroot + lvl * H * H, hbuf);
        k_score<<<Ncur / 2, 256, 0, stream>>>(hbuf, poolw + lvl * H, score, skey);
        k_pool<<<NB, 256, 0, stream>>>(hbuf, score, skey, ei, ei + ETOT, epk,
                                       lvl ? 1 : 0, (lvl < 2) ? 1 : 0,
                                       xbuf, g, n, k, (lvl == 0) ? 1 : 0);
        xin = xbuf;
    }
    k_head<<<NB, 128, 0, stream>>>(g, W1, b1, W2, b2, out);
}